// Round 1
// baseline (1561.224 us; speedup 1.0000x reference)
//
#include <hip/hip_runtime.h>
#include <math.h>

#define N_NODES 50000
#define E_EDGES 800000
#define E2 (E_EDGES + N_NODES)   // 850000 with self loops
#define FDIM 512
#define HID 256
#define HEADS 8
#define CDIM 32
#define LAYERS 3
#define GRAPHS 64
#define LN_EPS 1e-5f

// ---------------------------------------------------------------- CSR build
__global__ void k_count(const int* __restrict__ ei, int* __restrict__ cnt) {
    int e = blockIdx.x * 256 + threadIdx.x;
    if (e >= E2) return;
    int dst = (e < E_EDGES) ? ei[E_EDGES + e] : (e - E_EDGES);
    atomicAdd(&cnt[dst], 1);
}

__global__ void k_scan1(const int* __restrict__ cnt, int* __restrict__ part) {
    __shared__ int s[256];
    int t = threadIdx.x;
    int i = blockIdx.x * 256 + t;
    s[t] = (i < N_NODES) ? cnt[i] : 0;
    __syncthreads();
    for (int d = 128; d > 0; d >>= 1) {
        if (t < d) s[t] += s[t + d];
        __syncthreads();
    }
    if (t == 0) part[blockIdx.x] = s[0];
}

__global__ void k_scan2(int* __restrict__ part, int nb, int* __restrict__ rowptr) {
    __shared__ int s[256];
    int t = threadIdx.x;
    int v = (t < nb) ? part[t] : 0;
    s[t] = v;
    __syncthreads();
    for (int d = 1; d < 256; d <<= 1) {
        int x = (t >= d) ? s[t - d] : 0;
        __syncthreads();
        s[t] += x;
        __syncthreads();
    }
    if (t < nb) part[t] = s[t] - v;      // exclusive offsets per block
    if (t == 255) rowptr[N_NODES] = s[255];
}

__global__ void k_scan3(const int* __restrict__ cnt, const int* __restrict__ part,
                        int* __restrict__ rowptr) {
    __shared__ int s[256];
    int t = threadIdx.x;
    int i = blockIdx.x * 256 + t;
    int v = (i < N_NODES) ? cnt[i] : 0;
    s[t] = v;
    __syncthreads();
    for (int d = 1; d < 256; d <<= 1) {
        int x = (t >= d) ? s[t - d] : 0;
        __syncthreads();
        s[t] += x;
        __syncthreads();
    }
    if (i < N_NODES) rowptr[i] = part[blockIdx.x] + s[t] - v;
}

__global__ void k_fill(const int* __restrict__ ei, const int* __restrict__ rowptr,
                       int* __restrict__ fill, int* __restrict__ colv) {
    int e = blockIdx.x * 256 + threadIdx.x;
    if (e >= E2) return;
    int src, dst;
    if (e < E_EDGES) { src = ei[e]; dst = ei[E_EDGES + e]; }
    else             { src = dst = e - E_EDGES; }
    int pos = atomicAdd(&fill[dst], 1);
    colv[rowptr[dst] + pos] = src;
}

// ---------------------------------------------------------------- graph bounds
__global__ void k_bounds(const int* __restrict__ batch, int* __restrict__ rowstart) {
    int n = blockIdx.x * 256 + threadIdx.x;
    if (n >= N_NODES) return;
    int b = batch[n];
    int bp = (n == 0) ? -1 : batch[n - 1];
    for (int g = bp + 1; g <= b; ++g) rowstart[g] = n;
    if (n == N_NODES - 1) {
        for (int g = b + 1; g <= GRAPHS; ++g) rowstart[g] = N_NODES;
    }
}

// ---------------------------------------------------------------- fp32 tiled GEMM
// C[M,256] = A[M,K] @ B[K,256] (+ bias); BM=BN=64, BK=16, 256 thr, 4x4 micro.
template<int K>
__global__ __launch_bounds__(256) void k_gemm64(const float* __restrict__ A,
                                                const float* __restrict__ B,
                                                const float* __restrict__ bias,
                                                float* __restrict__ C, int M) {
    __shared__ float As[16][68];
    __shared__ float Bs[16][68];
    const int bm = blockIdx.x * 64;
    const int bn = blockIdx.y * 64;
    const int t  = threadIdx.x;
    const int tx = t & 15, ty = t >> 4;
    float acc[4][4] = {};

    for (int k0 = 0; k0 < K; k0 += 16) {
        {   // A tile 64x16: thread -> m = t>>2, kq = (t&3)*4
            int m  = t >> 2;
            int kq = (t & 3) * 4;
            int row = bm + m;
            float4 v = make_float4(0.f, 0.f, 0.f, 0.f);
            if (row < M) v = *(const float4*)(A + (size_t)row * K + k0 + kq);
            As[kq + 0][m] = v.x; As[kq + 1][m] = v.y;
            As[kq + 2][m] = v.z; As[kq + 3][m] = v.w;
        }
        {   // B tile 16x64: thread -> k = t>>4, nq = (t&15)*4
            int k  = t >> 4;
            int nq = (t & 15) * 4;
            float4 v = *(const float4*)(B + (size_t)(k0 + k) * HID + bn + nq);
            *(float4*)&Bs[k][nq] = v;
        }
        __syncthreads();
        #pragma unroll
        for (int kk = 0; kk < 16; ++kk) {
            float4 ra = *(const float4*)&As[kk][ty * 4];
            float4 rb = *(const float4*)&Bs[kk][tx * 4];
            float a4[4] = {ra.x, ra.y, ra.z, ra.w};
            float b4[4] = {rb.x, rb.y, rb.z, rb.w};
            #pragma unroll
            for (int i = 0; i < 4; ++i)
                #pragma unroll
                for (int j = 0; j < 4; ++j)
                    acc[i][j] += a4[i] * b4[j];
        }
        __syncthreads();
    }
    #pragma unroll
    for (int i = 0; i < 4; ++i) {
        int row = bm + ty * 4 + i;
        if (row >= M) continue;
        int col = bn + tx * 4;
        float4 o;
        o.x = acc[i][0]; o.y = acc[i][1]; o.z = acc[i][2]; o.w = acc[i][3];
        if (bias) {
            o.x += bias[col + 0]; o.y += bias[col + 1];
            o.z += bias[col + 2]; o.w += bias[col + 3];
        }
        *(float4*)(C + (size_t)row * HID + col) = o;
    }
}

// ---------------------------------------------------------------- attention scores
// asn[n,h] = dot(xh[n,h,:], a_src[h,:]); adn likewise. 1 wave / node.
__global__ __launch_bounds__(256) void k_scores(const float* __restrict__ xh,
                                                const float* __restrict__ a_src,
                                                const float* __restrict__ a_dst,
                                                float* __restrict__ asn,
                                                float* __restrict__ adn) {
    int wave = threadIdx.x >> 6, lane = threadIdx.x & 63;
    int n = blockIdx.x * 4 + wave;
    if (n >= N_NODES) return;
    int head = lane >> 3, part = lane & 7;
    const float4 v  = *(const float4*)(xh + (size_t)n * HID + head * CDIM + part * 4);
    const float4 ws = *(const float4*)(a_src + head * CDIM + part * 4);
    const float4 wd = *(const float4*)(a_dst + head * CDIM + part * 4);
    float ds_ = v.x * ws.x + v.y * ws.y + v.z * ws.z + v.w * ws.w;
    float dd_ = v.x * wd.x + v.y * wd.y + v.z * wd.z + v.w * wd.w;
    for (int d = 1; d < 8; d <<= 1) {
        ds_ += __shfl_xor(ds_, d);
        dd_ += __shfl_xor(dd_, d);
    }
    if (part == 0) {
        asn[n * HEADS + head] = ds_;
        adn[n * HEADS + head] = dd_;
    }
}

// ---------------------------------------------------------------- aggregation
// One wave per dst node; online softmax over its incoming-edge list.
__global__ __launch_bounds__(256) void k_aggregate(const float* __restrict__ xh,
                                                   const float* __restrict__ asn,
                                                   const float* __restrict__ adn,
                                                   const int* __restrict__ rowptr,
                                                   const int* __restrict__ colv,
                                                   float* __restrict__ out) {
    int wave = threadIdx.x >> 6, lane = threadIdx.x & 63;
    int n = blockIdx.x * 4 + wave;
    if (n >= N_NODES) return;
    int head = lane >> 3, part = lane & 7;
    float adn_h = adn[n * HEADS + head];
    int j0 = rowptr[n], j1 = rowptr[n + 1];
    float m = -INFINITY, ssum = 0.f;
    float a0 = 0.f, a1 = 0.f, a2 = 0.f, a3 = 0.f;
    for (int j = j0; j < j1; ++j) {
        int s = colv[j];
        float a = asn[s * HEADS + head] + adn_h;
        float e = (a > 0.f) ? a : 0.2f * a;            // leaky_relu 0.2
        float mn = fmaxf(m, e);
        float corr = __expf(m - mn);                   // exp(-inf)=0 first iter
        float p = __expf(e - mn);
        ssum = ssum * corr + p;
        const float4 v = *(const float4*)(xh + (size_t)s * HID + head * CDIM + part * 4);
        a0 = a0 * corr + p * v.x;
        a1 = a1 * corr + p * v.y;
        a2 = a2 * corr + p * v.z;
        a3 = a3 * corr + p * v.w;
        m = mn;
    }
    float inv = 1.f / (ssum + 1e-16f);
    float4 o = make_float4(a0 * inv, a1 * inv, a2 * inv, a3 * inv);
    *(float4*)(out + (size_t)n * HID + head * CDIM + part * 4) = o;
}

// ---------------------------------------------------------------- LN(+res+bias)+ReLU
// h <- relu(LN(h + gat_b + hres) * g + b), one wave per node (4 ch/lane).
__global__ __launch_bounds__(256) void k_ln(float* __restrict__ h,
                                            const float* __restrict__ hres,
                                            const float* __restrict__ gb,
                                            const float* __restrict__ g,
                                            const float* __restrict__ b) {
    int wave = threadIdx.x >> 6, lane = threadIdx.x & 63;
    int n = blockIdx.x * 4 + wave;
    if (n >= N_NODES) return;
    int c0 = lane * 4;
    float4 v = *(float4*)(h + (size_t)n * HID + c0);
    float4 r = *(const float4*)(hres + (size_t)n * HID + c0);
    float4 gb4 = *(const float4*)(gb + c0);
    v.x += r.x + gb4.x; v.y += r.y + gb4.y;
    v.z += r.z + gb4.z; v.w += r.w + gb4.w;
    float s = v.x + v.y + v.z + v.w;
    for (int d = 1; d < 64; d <<= 1) s += __shfl_xor(s, d);
    float mu = s * (1.f / HID);
    float d0 = v.x - mu, d1 = v.y - mu, d2 = v.z - mu, d3 = v.w - mu;
    float q = d0 * d0 + d1 * d1 + d2 * d2 + d3 * d3;
    for (int d = 1; d < 64; d <<= 1) q += __shfl_xor(q, d);
    float rstd = rsqrtf(q * (1.f / HID) + LN_EPS);
    float4 gg = *(const float4*)(g + c0);
    float4 bb = *(const float4*)(b + c0);
    float4 o;
    o.x = fmaxf(d0 * rstd * gg.x + bb.x, 0.f);
    o.y = fmaxf(d1 * rstd * gg.y + bb.y, 0.f);
    o.z = fmaxf(d2 * rstd * gg.z + bb.z, 0.f);
    o.w = fmaxf(d3 * rstd * gg.w + bb.w, 0.f);
    *(float4*)(h + (size_t)n * HID + c0) = o;
}

// ---------------------------------------------------------------- pooling
__global__ __launch_bounds__(256) void k_pool(const float* __restrict__ h,
                                              const int* __restrict__ rowstart,
                                              float* __restrict__ hcat) {
    int g = blockIdx.x, c = threadIdx.x;
    int s0 = rowstart[g], s1 = rowstart[g + 1];
    float sum = 0.f, mx = -INFINITY;
    for (int n = s0; n < s1; ++n) {
        float v = h[(size_t)n * HID + c];
        sum += v;
        mx = fmaxf(mx, v);
    }
    float cntf = (float)(s1 - s0);
    hcat[(size_t)g * (2 * HID) + c] = sum / fmaxf(cntf, 1.f);
    hcat[(size_t)g * (2 * HID) + HID + c] = mx;
}

__global__ __launch_bounds__(256) void k_pool_gemm(const float* __restrict__ hcat,
                                                   const float* __restrict__ W,
                                                   const float* __restrict__ bias,
                                                   float* __restrict__ out) {
    int g = blockIdx.x, c = threadIdx.x;
    const float* hg = hcat + (size_t)g * (2 * HID);
    float acc = bias[c];
    for (int k = 0; k < 2 * HID; ++k)
        acc += hg[k] * W[(size_t)k * HID + c];
    out[(size_t)g * HID + c] = fmaxf(acc, 0.f);
}

// ---------------------------------------------------------------- launch
extern "C" void kernel_launch(void* const* d_in, const int* in_sizes, int n_in,
                              void* d_out, int out_size, void* d_ws, size_t ws_size,
                              hipStream_t stream) {
    const float* x       = (const float*)d_in[0];
    const int*   ei      = (const int*)d_in[1];
    const int*   batch   = (const int*)d_in[2];
    const float* in_w    = (const float*)d_in[3];
    const float* in_b    = (const float*)d_in[4];
    const float* gat_w   = (const float*)d_in[5];
    const float* att_src = (const float*)d_in[6];
    const float* att_dst = (const float*)d_in[7];
    const float* gat_b   = (const float*)d_in[8];
    const float* res_w   = (const float*)d_in[9];
    const float* res_b   = (const float*)d_in[10];
    const float* ln_g    = (const float*)d_in[11];
    const float* ln_b    = (const float*)d_in[12];
    const float* pool_w  = (const float*)d_in[13];
    const float* pool_b  = (const float*)d_in[14];
    float* out = (float*)d_out;

    char* ws = (char*)d_ws;
    size_t off = 0;
    auto alloc = [&](size_t bytes) -> char* {
        char* p = ws + off;
        off = (off + bytes + 255) & ~(size_t)255;
        return p;
    };
    float* h      = (float*)alloc((size_t)N_NODES * HID * 4);
    float* xh     = (float*)alloc((size_t)N_NODES * HID * 4);
    float* hres   = (float*)alloc((size_t)N_NODES * HID * 4);
    float* asn    = (float*)alloc((size_t)N_NODES * HEADS * 4);
    float* adn    = (float*)alloc((size_t)N_NODES * HEADS * 4);
    int*   cnt    = (int*)alloc((size_t)N_NODES * 4);
    int*   fill   = (int*)alloc((size_t)N_NODES * 4);
    int*   rowptr = (int*)alloc((size_t)(N_NODES + 1) * 4);
    int*   colv   = (int*)alloc((size_t)E2 * 4);
    int*   part   = (int*)alloc(256 * 4);
    int*   rowstart = (int*)alloc((size_t)(GRAPHS + 1) * 4);
    float* hcat   = (float*)alloc((size_t)GRAPHS * 2 * HID * 4);

    hipMemsetAsync(cnt, 0, (size_t)N_NODES * 4, stream);
    hipMemsetAsync(fill, 0, (size_t)N_NODES * 4, stream);

    const int ge = (E2 + 255) / 256;
    const int nb = (N_NODES + 255) / 256;
    k_count<<<ge, 256, 0, stream>>>(ei, cnt);
    k_scan1<<<nb, 256, 0, stream>>>(cnt, part);
    k_scan2<<<1, 256, 0, stream>>>(part, nb, rowptr);
    k_scan3<<<nb, 256, 0, stream>>>(cnt, part, rowptr);
    k_fill<<<ge, 256, 0, stream>>>(ei, rowptr, fill, colv);
    k_bounds<<<nb, 256, 0, stream>>>(batch, rowstart);

    dim3 gg((N_NODES + 63) / 64, HID / 64);
    k_gemm64<FDIM><<<gg, 256, 0, stream>>>(x, in_w, in_b, h, N_NODES);

    const int nw = (N_NODES + 3) / 4;
    for (int i = 0; i < LAYERS; ++i) {
        k_gemm64<HID><<<gg, 256, 0, stream>>>(h, res_w + (size_t)i * HID * HID,
                                              res_b + (size_t)i * HID, hres, N_NODES);
        k_gemm64<HID><<<gg, 256, 0, stream>>>(h, gat_w + (size_t)i * HID * HID,
                                              nullptr, xh, N_NODES);
        k_scores<<<nw, 256, 0, stream>>>(xh, att_src + (size_t)i * HEADS * CDIM,
                                         att_dst + (size_t)i * HEADS * CDIM, asn, adn);
        k_aggregate<<<nw, 256, 0, stream>>>(xh, asn, adn, rowptr, colv, h);
        k_ln<<<nw, 256, 0, stream>>>(h, hres, gat_b + (size_t)i * HID,
                                     ln_g + (size_t)i * HID, ln_b + (size_t)i * HID);
    }
    k_pool<<<GRAPHS, 256, 0, stream>>>(h, rowstart, hcat);
    k_pool_gemm<<<GRAPHS, 256, 0, stream>>>(hcat, pool_w, pool_b, out);
}

// Round 2
// 756.521 us; speedup vs baseline: 2.0637x; 2.0637x over previous
//
#include <hip/hip_runtime.h>
#include <math.h>

#define N_NODES 50000
#define E_EDGES 800000
#define E2 (E_EDGES + N_NODES)   // 850000 with self loops
#define M_PAD 50048              // 391 * 128
#define FDIM 512
#define HID 256
#define HEADS 8
#define CDIM 32
#define LAYERS 3
#define GRAPHS 64
#define LN_EPS 1e-5f
#define POOL_P 16

typedef unsigned short ushort_t;
typedef __attribute__((ext_vector_type(8))) short short8v;
typedef __attribute__((ext_vector_type(4))) float f32x4;

__device__ __forceinline__ float bf2f(ushort_t u) {
    union { unsigned int i; float f; } v;
    v.i = ((unsigned int)u) << 16;
    return v.f;
}
__device__ __forceinline__ ushort_t f2bf(float f) {
    union { float f; unsigned int u; } v;
    v.f = f;
    unsigned int r = (v.u + 0x7FFFu + ((v.u >> 16) & 1u)) >> 16;
    return (ushort_t)r;
}
__device__ __forceinline__ void gload_lds16(const void* g, void* l) {
    __builtin_amdgcn_global_load_lds(
        (const __attribute__((address_space(1))) void*)g,
        (__attribute__((address_space(3))) void*)l, 16, 0, 0);
}

// ---------------------------------------------------------------- CSR build
__global__ void k_count(const int* __restrict__ ei, int* __restrict__ cnt) {
    int e = blockIdx.x * 256 + threadIdx.x;
    if (e >= E2) return;
    int dst = (e < E_EDGES) ? ei[E_EDGES + e] : (e - E_EDGES);
    atomicAdd(&cnt[dst], 1);
}

__global__ void k_scan1(const int* __restrict__ cnt, int* __restrict__ part) {
    __shared__ int s[256];
    int t = threadIdx.x;
    int i = blockIdx.x * 256 + t;
    s[t] = (i < N_NODES) ? cnt[i] : 0;
    __syncthreads();
    for (int d = 128; d > 0; d >>= 1) {
        if (t < d) s[t] += s[t + d];
        __syncthreads();
    }
    if (t == 0) part[blockIdx.x] = s[0];
}

__global__ void k_scan2(int* __restrict__ part, int nb, int* __restrict__ rowptr) {
    __shared__ int s[256];
    int t = threadIdx.x;
    int v = (t < nb) ? part[t] : 0;
    s[t] = v;
    __syncthreads();
    for (int d = 1; d < 256; d <<= 1) {
        int x = (t >= d) ? s[t - d] : 0;
        __syncthreads();
        s[t] += x;
        __syncthreads();
    }
    if (t < nb) part[t] = s[t] - v;
    if (t == 255) rowptr[N_NODES] = s[255];
}

__global__ void k_scan3(const int* __restrict__ cnt, const int* __restrict__ part,
                        int* __restrict__ rowptr) {
    __shared__ int s[256];
    int t = threadIdx.x;
    int i = blockIdx.x * 256 + t;
    int v = (i < N_NODES) ? cnt[i] : 0;
    s[t] = v;
    __syncthreads();
    for (int d = 1; d < 256; d <<= 1) {
        int x = (t >= d) ? s[t - d] : 0;
        __syncthreads();
        s[t] += x;
        __syncthreads();
    }
    if (i < N_NODES) rowptr[i] = part[blockIdx.x] + s[t] - v;
}

__global__ void k_fill(const int* __restrict__ ei, const int* __restrict__ rowptr,
                       int* __restrict__ fill, int* __restrict__ colv) {
    int e = blockIdx.x * 256 + threadIdx.x;
    if (e >= E2) return;
    int src, dst;
    if (e < E_EDGES) { src = ei[e]; dst = ei[E_EDGES + e]; }
    else             { src = dst = e - E_EDGES; }
    int pos = atomicAdd(&fill[dst], 1);
    colv[rowptr[dst] + pos] = src;
}

__global__ void k_bounds(const int* __restrict__ batch, int* __restrict__ rowstart) {
    int n = blockIdx.x * 256 + threadIdx.x;
    if (n >= N_NODES) return;
    int b = batch[n];
    int bp = (n == 0) ? -1 : batch[n - 1];
    for (int g = bp + 1; g <= b; ++g) rowstart[g] = n;
    if (n == N_NODES - 1) {
        for (int g = b + 1; g <= GRAPHS; ++g) rowstart[g] = N_NODES;
    }
}

// ---------------------------------------------------------------- conversions
// x fp32 [N,512] -> bf16 [M_PAD,512], pad rows zeroed
__global__ __launch_bounds__(256) void k_cast_x(const float* __restrict__ x,
                                                ushort_t* __restrict__ xb) {
    long long i8 = ((long long)blockIdx.x * 256 + threadIdx.x) * 8;
    if (i8 >= (long long)M_PAD * FDIM) return;
    int row = (int)(i8 >> 9);
    ushort_t o[8];
    if (row < N_NODES) {
        const float* p = x + i8;
        #pragma unroll
        for (int j = 0; j < 8; ++j) o[j] = f2bf(p[j]);
    } else {
        #pragma unroll
        for (int j = 0; j < 8; ++j) o[j] = 0;
    }
    *(short8v*)(xb + i8) = *(short8v*)o;
}

// W fp32 [K,256] -> WT bf16 [256,K]
__global__ __launch_bounds__(256) void k_wtrans(const float* __restrict__ W,
                                                ushort_t* __restrict__ WT, int K) {
    int i = blockIdx.x * 256 + threadIdx.x;
    if (i >= K * HID) return;
    int k = i >> 8, n = i & 255;
    WT[(size_t)n * K + k] = f2bf(W[i]);
}

// ---------------------------------------------------------------- bf16 MFMA GEMM
// C[M,256] = A[M,K] @ B[K,256]; A bf16 [M_PAD,K], BT bf16 [256,K].
// 128x128 tile, BK=32, 256 thr (4 waves 2x2). LDS linear, global source pre-swizzled.
template<int K>
__global__ __launch_bounds__(256) void k_gemm_bf16(const ushort_t* __restrict__ A,
                                                   const ushort_t* __restrict__ BT,
                                                   const float* __restrict__ bias,
                                                   ushort_t* __restrict__ Cb, int M) {
    __shared__ char lds[16384] __attribute__((aligned(16)));
    const int bm = blockIdx.x * 128;
    const int bn = blockIdx.y * 128;
    const int t = threadIdx.x, w = t >> 6, l = t & 63;
    const int wr = w >> 1, wc = w & 1;

    // staging descriptors: chunk c -> (row=c>>2, slot=c&3), content k-block = slot^((row>>1)&3)
    const int c1 = t, c2 = t + 256;
    const int ar1 = c1 >> 2, as1 = (c1 & 3) ^ ((ar1 >> 1) & 3);
    const int ar2 = c2 >> 2, as2 = (c2 & 3) ^ ((ar2 >> 1) & 3);
    const ushort_t* pa1 = A + (size_t)(bm + ar1) * K + as1 * 8;
    const ushort_t* pa2 = A + (size_t)(bm + ar2) * K + as2 * 8;
    const ushort_t* pb1 = BT + (size_t)(bn + ar1) * K + as1 * 8;
    const ushort_t* pb2 = BT + (size_t)(bn + ar2) * K + as2 * 8;
    char* la1 = lds + w * 1024;
    char* la2 = lds + 4096 + w * 1024;
    char* lb1 = lds + 8192 + w * 1024;
    char* lb2 = lds + 12288 + w * 1024;

    // fragment read byte offsets (swizzled)
    int aoff[4], boff[4];
    const int kb = l >> 4;
    #pragma unroll
    for (int mi = 0; mi < 4; ++mi) {
        int r = wr * 64 + mi * 16 + (l & 15);
        aoff[mi] = r * 64 + ((kb ^ ((r >> 1) & 3)) << 4);
        int c = wc * 64 + mi * 16 + (l & 15);
        boff[mi] = 8192 + c * 64 + ((kb ^ ((c >> 1) & 3)) << 4);
    }

    f32x4 acc[4][4] = {};
    for (int k0 = 0; k0 < K; k0 += 32) {
        gload_lds16(pa1 + k0, la1);
        gload_lds16(pa2 + k0, la2);
        gload_lds16(pb1 + k0, lb1);
        gload_lds16(pb2 + k0, lb2);
        __syncthreads();
        short8v a[4], b[4];
        #pragma unroll
        for (int mi = 0; mi < 4; ++mi) a[mi] = *(const short8v*)(lds + aoff[mi]);
        #pragma unroll
        for (int ni = 0; ni < 4; ++ni) b[ni] = *(const short8v*)(lds + boff[ni]);
        #pragma unroll
        for (int mi = 0; mi < 4; ++mi)
            #pragma unroll
            for (int ni = 0; ni < 4; ++ni)
                acc[mi][ni] = __builtin_amdgcn_mfma_f32_16x16x32_bf16(
                    a[mi], b[ni], acc[mi][ni], 0, 0, 0);
        __syncthreads();
    }

    #pragma unroll
    for (int mi = 0; mi < 4; ++mi) {
        int row = bm + wr * 64 + mi * 16 + (l >> 4) * 4;
        #pragma unroll
        for (int ni = 0; ni < 4; ++ni) {
            int col = bn + wc * 64 + ni * 16 + (l & 15);
            float bv = bias ? bias[col] : 0.f;
            #pragma unroll
            for (int r = 0; r < 4; ++r) {
                if (row + r < M)
                    Cb[(size_t)(row + r) * HID + col] = f2bf(acc[mi][ni][r] + bv);
            }
        }
    }
}

// ---------------------------------------------------------------- attention scores
__global__ __launch_bounds__(256) void k_scores(const ushort_t* __restrict__ xhb,
                                                const float* __restrict__ a_src,
                                                const float* __restrict__ a_dst,
                                                float* __restrict__ asn,
                                                float* __restrict__ adn) {
    int wave = threadIdx.x >> 6, lane = threadIdx.x & 63;
    int n = blockIdx.x * 4 + wave;
    if (n >= N_NODES) return;
    int head = lane >> 3, part = lane & 7;
    ushort4 u = *(const ushort4*)(xhb + (size_t)n * HID + head * CDIM + part * 4);
    float vx = bf2f(u.x), vy = bf2f(u.y), vz = bf2f(u.z), vw = bf2f(u.w);
    const float4 ws = *(const float4*)(a_src + head * CDIM + part * 4);
    const float4 wd = *(const float4*)(a_dst + head * CDIM + part * 4);
    float ds_ = vx * ws.x + vy * ws.y + vz * ws.z + vw * ws.w;
    float dd_ = vx * wd.x + vy * wd.y + vz * wd.z + vw * wd.w;
    for (int d = 1; d < 8; d <<= 1) {
        ds_ += __shfl_xor(ds_, d);
        dd_ += __shfl_xor(dd_, d);
    }
    if (part == 0) {
        asn[n * HEADS + head] = ds_;
        adn[n * HEADS + head] = dd_;
    }
}

// ---------------------------------------------------------------- aggregation + residual + LN + ReLU
__global__ __launch_bounds__(256) void k_agg_ln(const ushort_t* __restrict__ xhb,
                                                const float* __restrict__ asn,
                                                const float* __restrict__ adn,
                                                const int* __restrict__ rowptr,
                                                const int* __restrict__ colv,
                                                const ushort_t* __restrict__ hresb,
                                                const float* __restrict__ gb,
                                                const float* __restrict__ g,
                                                const float* __restrict__ b,
                                                ushort_t* __restrict__ hb) {
    int wave = threadIdx.x >> 6, lane = threadIdx.x & 63;
    int n = blockIdx.x * 4 + wave;
    if (n >= N_NODES) return;
    int head = lane >> 3, part = lane & 7;
    int c0 = head * CDIM + part * 4;
    float adn_h = adn[n * HEADS + head];
    int j0 = rowptr[n], j1 = rowptr[n + 1];
    float m = -INFINITY, ssum = 0.f;
    float a0 = 0.f, a1 = 0.f, a2 = 0.f, a3 = 0.f;
    for (int j = j0; j < j1; ++j) {
        int s = colv[j];
        float a = asn[s * HEADS + head] + adn_h;
        float e = (a > 0.f) ? a : 0.2f * a;
        float mn = fmaxf(m, e);
        float corr = __expf(m - mn);
        float p = __expf(e - mn);
        ssum = ssum * corr + p;
        ushort4 u = *(const ushort4*)(xhb + (size_t)s * HID + c0);
        a0 = a0 * corr + p * bf2f(u.x);
        a1 = a1 * corr + p * bf2f(u.y);
        a2 = a2 * corr + p * bf2f(u.z);
        a3 = a3 * corr + p * bf2f(u.w);
        m = mn;
    }
    float inv = 1.f / (ssum + 1e-16f);
    ushort4 hr = *(const ushort4*)(hresb + (size_t)n * HID + c0);
    float4 gb4 = *(const float4*)(gb + c0);
    float v0 = a0 * inv + bf2f(hr.x) + gb4.x;
    float v1 = a1 * inv + bf2f(hr.y) + gb4.y;
    float v2 = a2 * inv + bf2f(hr.z) + gb4.z;
    float v3 = a3 * inv + bf2f(hr.w) + gb4.w;
    float s = v0 + v1 + v2 + v3;
    for (int d = 1; d < 64; d <<= 1) s += __shfl_xor(s, d);
    float mu = s * (1.f / HID);
    float d0 = v0 - mu, d1 = v1 - mu, d2 = v2 - mu, d3 = v3 - mu;
    float q = d0 * d0 + d1 * d1 + d2 * d2 + d3 * d3;
    for (int d = 1; d < 64; d <<= 1) q += __shfl_xor(q, d);
    float rstd = rsqrtf(q * (1.f / HID) + LN_EPS);
    float4 gg = *(const float4*)(g + c0);
    float4 bb = *(const float4*)(b + c0);
    ushort_t o[4];
    o[0] = f2bf(fmaxf(d0 * rstd * gg.x + bb.x, 0.f));
    o[1] = f2bf(fmaxf(d1 * rstd * gg.y + bb.y, 0.f));
    o[2] = f2bf(fmaxf(d2 * rstd * gg.z + bb.z, 0.f));
    o[3] = f2bf(fmaxf(d3 * rstd * gg.w + bb.w, 0.f));
    *(ushort4*)(hb + (size_t)n * HID + c0) = *(ushort4*)o;
}

// ---------------------------------------------------------------- pooling (2-stage)
__global__ __launch_bounds__(256) void k_pool1(const ushort_t* __restrict__ hb,
                                               const int* __restrict__ rowstart,
                                               float* __restrict__ part) {
    int g = blockIdx.x, p = blockIdx.y, c = threadIdx.x;
    int s0 = rowstart[g], s1 = rowstart[g + 1];
    float sum = 0.f, mx = -INFINITY;
    for (int n = s0 + p; n < s1; n += POOL_P) {
        float v = bf2f(hb[(size_t)n * HID + c]);
        sum += v;
        mx = fmaxf(mx, v);
    }
    float* pp = part + (size_t)(g * POOL_P + p) * 512;
    pp[c] = sum;
    pp[256 + c] = mx;
}

__global__ __launch_bounds__(256) void k_pool2(const float* __restrict__ part,
                                               const int* __restrict__ rowstart,
                                               float* __restrict__ hcat) {
    int g = blockIdx.x, c = threadIdx.x;
    float sum = 0.f, mx = -INFINITY;
    for (int p = 0; p < POOL_P; ++p) {
        const float* pp = part + (size_t)(g * POOL_P + p) * 512;
        sum += pp[c];
        mx = fmaxf(mx, pp[256 + c]);
    }
    float cntf = (float)(rowstart[g + 1] - rowstart[g]);
    hcat[(size_t)g * (2 * HID) + c] = sum / fmaxf(cntf, 1.f);
    hcat[(size_t)g * (2 * HID) + HID + c] = mx;
}

__global__ __launch_bounds__(256) void k_pool_gemm(const float* __restrict__ hcat,
                                                   const float* __restrict__ W,
                                                   const float* __restrict__ bias,
                                                   float* __restrict__ out) {
    int g = blockIdx.x, c = threadIdx.x;
    const float* hg = hcat + (size_t)g * (2 * HID);
    float acc = bias[c];
    for (int k = 0; k < 2 * HID; ++k)
        acc += hg[k] * W[(size_t)k * HID + c];
    out[(size_t)g * HID + c] = fmaxf(acc, 0.f);
}

// ---------------------------------------------------------------- launch
extern "C" void kernel_launch(void* const* d_in, const int* in_sizes, int n_in,
                              void* d_out, int out_size, void* d_ws, size_t ws_size,
                              hipStream_t stream) {
    const float* x       = (const float*)d_in[0];
    const int*   ei      = (const int*)d_in[1];
    const int*   batch   = (const int*)d_in[2];
    const float* in_w    = (const float*)d_in[3];
    const float* in_b    = (const float*)d_in[4];
    const float* gat_w   = (const float*)d_in[5];
    const float* att_src = (const float*)d_in[6];
    const float* att_dst = (const float*)d_in[7];
    const float* gat_b   = (const float*)d_in[8];
    const float* res_w   = (const float*)d_in[9];
    const float* res_b   = (const float*)d_in[10];
    const float* ln_g    = (const float*)d_in[11];
    const float* ln_b    = (const float*)d_in[12];
    const float* pool_w  = (const float*)d_in[13];
    const float* pool_b  = (const float*)d_in[14];
    float* out = (float*)d_out;

    char* ws = (char*)d_ws;
    size_t off = 0;
    auto alloc = [&](size_t bytes) -> char* {
        char* p = ws + off;
        off = (off + bytes + 255) & ~(size_t)255;
        return p;
    };
    ushort_t* xb    = (ushort_t*)alloc((size_t)M_PAD * FDIM * 2);
    ushort_t* hb    = (ushort_t*)alloc((size_t)M_PAD * HID * 2);
    ushort_t* xhb   = (ushort_t*)alloc((size_t)M_PAD * HID * 2);
    ushort_t* hresb = (ushort_t*)alloc((size_t)M_PAD * HID * 2);
    float* asn      = (float*)alloc((size_t)N_NODES * HEADS * 4);
    float* adn      = (float*)alloc((size_t)N_NODES * HEADS * 4);
    int*   cnt      = (int*)alloc((size_t)N_NODES * 4);
    int*   fill     = (int*)alloc((size_t)N_NODES * 4);
    int*   rowptr   = (int*)alloc((size_t)(N_NODES + 1) * 4);
    int*   colv     = (int*)alloc((size_t)E2 * 4);
    int*   part     = (int*)alloc(256 * 4);
    int*   rowstart = (int*)alloc((size_t)(GRAPHS + 1) * 4);
    ushort_t* wt_in = (ushort_t*)alloc((size_t)HID * FDIM * 2);
    ushort_t* wt_gat= (ushort_t*)alloc((size_t)LAYERS * HID * HID * 2);
    ushort_t* wt_res= (ushort_t*)alloc((size_t)LAYERS * HID * HID * 2);
    float* poolpart = (float*)alloc((size_t)GRAPHS * POOL_P * 512 * 4);
    float* hcat     = (float*)alloc((size_t)GRAPHS * 2 * HID * 4);

    hipMemsetAsync(cnt, 0, (size_t)N_NODES * 4, stream);
    hipMemsetAsync(fill, 0, (size_t)N_NODES * 4, stream);

    const int ge = (E2 + 255) / 256;
    const int nb = (N_NODES + 255) / 256;
    k_count<<<ge, 256, 0, stream>>>(ei, cnt);
    k_scan1<<<nb, 256, 0, stream>>>(cnt, part);
    k_scan2<<<1, 256, 0, stream>>>(part, nb, rowptr);
    k_scan3<<<nb, 256, 0, stream>>>(cnt, part, rowptr);
    k_fill<<<ge, 256, 0, stream>>>(ei, rowptr, fill, colv);
    k_bounds<<<nb, 256, 0, stream>>>(batch, rowstart);

    // conversions
    k_cast_x<<<(int)(((size_t)M_PAD * FDIM / 8 + 255) / 256), 256, 0, stream>>>(x, xb);
    k_wtrans<<<(FDIM * HID + 255) / 256, 256, 0, stream>>>(in_w, wt_in, FDIM);
    for (int i = 0; i < LAYERS; ++i) {
        k_wtrans<<<(HID * HID + 255) / 256, 256, 0, stream>>>(
            gat_w + (size_t)i * HID * HID, wt_gat + (size_t)i * HID * HID, HID);
        k_wtrans<<<(HID * HID + 255) / 256, 256, 0, stream>>>(
            res_w + (size_t)i * HID * HID, wt_res + (size_t)i * HID * HID, HID);
    }

    dim3 gg(M_PAD / 128, 2);
    k_gemm_bf16<FDIM><<<gg, 256, 0, stream>>>(xb, wt_in, in_b, hb, N_NODES);

    const int nw = (N_NODES + 3) / 4;
    for (int i = 0; i < LAYERS; ++i) {
        k_gemm_bf16<HID><<<gg, 256, 0, stream>>>(hb, wt_res + (size_t)i * HID * HID,
                                                 res_b + (size_t)i * HID, hresb, N_NODES);
        k_gemm_bf16<HID><<<gg, 256, 0, stream>>>(hb, wt_gat + (size_t)i * HID * HID,
                                                 nullptr, xhb, N_NODES);
        k_scores<<<nw, 256, 0, stream>>>(xhb, att_src + (size_t)i * HEADS * CDIM,
                                         att_dst + (size_t)i * HEADS * CDIM, asn, adn);
        k_agg_ln<<<nw, 256, 0, stream>>>(xhb, asn, adn, rowptr, colv, hresb,
                                         gat_b + (size_t)i * HID,
                                         ln_g + (size_t)i * HID,
                                         ln_b + (size_t)i * HID, hb);
    }
    dim3 pg(GRAPHS, POOL_P);
    k_pool1<<<pg, 256, 0, stream>>>(hb, rowstart, poolpart);
    k_pool2<<<GRAPHS, 256, 0, stream>>>(poolpart, rowstart, hcat);
    k_pool_gemm<<<GRAPHS, 256, 0, stream>>>(hcat, pool_w, pool_b, out);
}

// Round 3
// 609.688 us; speedup vs baseline: 2.5607x; 1.2408x over previous
//
#include <hip/hip_runtime.h>
#include <math.h>

#define N_NODES 50000
#define E_EDGES 800000
#define E2 (E_EDGES + N_NODES)   // 850000 with self loops
#define M_PAD 50048              // 391 * 128
#define FDIM 512
#define HID 256
#define HEADS 8
#define CDIM 32
#define LAYERS 3
#define GRAPHS 64
#define LN_EPS 1e-5f
#define POOL_P 16

typedef unsigned short ushort_t;
typedef __attribute__((ext_vector_type(8))) short short8v;
typedef __attribute__((ext_vector_type(4))) float f32x4;

__device__ __forceinline__ float bf2f(ushort_t u) {
    union { unsigned int i; float f; } v;
    v.i = ((unsigned int)u) << 16;
    return v.f;
}
__device__ __forceinline__ ushort_t f2bf(float f) {
    union { float f; unsigned int u; } v;
    v.f = f;
    unsigned int r = (v.u + 0x7FFFu + ((v.u >> 16) & 1u)) >> 16;
    return (ushort_t)r;
}
__device__ __forceinline__ void gload_lds16(const void* g, void* l) {
    __builtin_amdgcn_global_load_lds(
        (const __attribute__((address_space(1))) void*)g,
        (__attribute__((address_space(3))) void*)l, 16, 0, 0);
}

// ---------------------------------------------------------------- CSR build
__global__ void k_count(const int* __restrict__ ei, int* __restrict__ cnt) {
    int e = blockIdx.x * 256 + threadIdx.x;
    if (e >= E2) return;
    int dst = (e < E_EDGES) ? ei[E_EDGES + e] : (e - E_EDGES);
    atomicAdd(&cnt[dst], 1);
}

__global__ void k_scan1(const int* __restrict__ cnt, int* __restrict__ part) {
    __shared__ int s[256];
    int t = threadIdx.x;
    int i = blockIdx.x * 256 + t;
    s[t] = (i < N_NODES) ? cnt[i] : 0;
    __syncthreads();
    for (int d = 128; d > 0; d >>= 1) {
        if (t < d) s[t] += s[t + d];
        __syncthreads();
    }
    if (t == 0) part[blockIdx.x] = s[0];
}

__global__ void k_scan2(int* __restrict__ part, int nb, int* __restrict__ rowptr) {
    __shared__ int s[256];
    int t = threadIdx.x;
    int v = (t < nb) ? part[t] : 0;
    s[t] = v;
    __syncthreads();
    for (int d = 1; d < 256; d <<= 1) {
        int x = (t >= d) ? s[t - d] : 0;
        __syncthreads();
        s[t] += x;
        __syncthreads();
    }
    if (t < nb) part[t] = s[t] - v;
    if (t == 255) rowptr[N_NODES] = s[255];
}

__global__ void k_scan3(const int* __restrict__ cnt, const int* __restrict__ part,
                        int* __restrict__ rowptr) {
    __shared__ int s[256];
    int t = threadIdx.x;
    int i = blockIdx.x * 256 + t;
    int v = (i < N_NODES) ? cnt[i] : 0;
    s[t] = v;
    __syncthreads();
    for (int d = 1; d < 256; d <<= 1) {
        int x = (t >= d) ? s[t - d] : 0;
        __syncthreads();
        s[t] += x;
        __syncthreads();
    }
    if (i < N_NODES) rowptr[i] = part[blockIdx.x] + s[t] - v;
}

__global__ void k_fill(const int* __restrict__ ei, const int* __restrict__ rowptr,
                       int* __restrict__ fill, int* __restrict__ colv) {
    int e = blockIdx.x * 256 + threadIdx.x;
    if (e >= E2) return;
    int src, dst;
    if (e < E_EDGES) { src = ei[e]; dst = ei[E_EDGES + e]; }
    else             { src = dst = e - E_EDGES; }
    int pos = atomicAdd(&fill[dst], 1);
    colv[rowptr[dst] + pos] = src;
}

__global__ void k_bounds(const int* __restrict__ batch, int* __restrict__ rowstart) {
    int n = blockIdx.x * 256 + threadIdx.x;
    if (n >= N_NODES) return;
    int b = batch[n];
    int bp = (n == 0) ? -1 : batch[n - 1];
    for (int g = bp + 1; g <= b; ++g) rowstart[g] = n;
    if (n == N_NODES - 1) {
        for (int g = b + 1; g <= GRAPHS; ++g) rowstart[g] = N_NODES;
    }
}

// ---------------------------------------------------------------- conversions
__global__ __launch_bounds__(256) void k_cast_x(const float* __restrict__ x,
                                                ushort_t* __restrict__ xb) {
    long long i8 = ((long long)blockIdx.x * 256 + threadIdx.x) * 8;
    if (i8 >= (long long)M_PAD * FDIM) return;
    int row = (int)(i8 >> 9);
    ushort_t o[8];
    if (row < N_NODES) {
        const float* p = x + i8;
        #pragma unroll
        for (int j = 0; j < 8; ++j) o[j] = f2bf(p[j]);
    } else {
        #pragma unroll
        for (int j = 0; j < 8; ++j) o[j] = 0;
    }
    *(short8v*)(xb + i8) = *(short8v*)o;
}

// W fp32 [K,256] -> WT bf16 [256,K] at dst (dst may be an offset into a larger table)
__global__ __launch_bounds__(256) void k_wtrans(const float* __restrict__ W,
                                                ushort_t* __restrict__ WT, int K) {
    int i = blockIdx.x * 256 + threadIdx.x;
    if (i >= K * HID) return;
    int k = i >> 8, n = i & 255;
    WT[(size_t)n * K + k] = f2bf(W[i]);
}

// ---------------------------------------------------------------- bf16 MFMA GEMM
// C[:, bn..bn+127] of A[M_PAD,K] @ BT^T, BT bf16 [NCOLS,K] (row n = output col n).
// Logical col < 256 -> C0 (+bias0), >= 256 -> C1 at col-256 (+bias1). 128x128 tile.
template<int K>
__global__ __launch_bounds__(256) void k_gemm_bf16(const ushort_t* __restrict__ A,
                                                   const ushort_t* __restrict__ BT,
                                                   const float* __restrict__ bias0,
                                                   const float* __restrict__ bias1,
                                                   ushort_t* __restrict__ C0,
                                                   ushort_t* __restrict__ C1, int M) {
    __shared__ char lds[16384] __attribute__((aligned(16)));
    const int bm = blockIdx.x * 128;
    const int bn = blockIdx.y * 128;
    const int t = threadIdx.x, w = t >> 6, l = t & 63;
    const int wr = w >> 1, wc = w & 1;

    const int c1 = t, c2 = t + 256;
    const int ar1 = c1 >> 2, as1 = (c1 & 3) ^ ((ar1 >> 1) & 3);
    const int ar2 = c2 >> 2, as2 = (c2 & 3) ^ ((ar2 >> 1) & 3);
    const ushort_t* pa1 = A + (size_t)(bm + ar1) * K + as1 * 8;
    const ushort_t* pa2 = A + (size_t)(bm + ar2) * K + as2 * 8;
    const ushort_t* pb1 = BT + (size_t)(bn + ar1) * K + as1 * 8;
    const ushort_t* pb2 = BT + (size_t)(bn + ar2) * K + as2 * 8;
    char* la1 = lds + w * 1024;
    char* la2 = lds + 4096 + w * 1024;
    char* lb1 = lds + 8192 + w * 1024;
    char* lb2 = lds + 12288 + w * 1024;

    int aoff[4], boff[4];
    const int kb = l >> 4;
    #pragma unroll
    for (int mi = 0; mi < 4; ++mi) {
        int r = wr * 64 + mi * 16 + (l & 15);
        aoff[mi] = r * 64 + ((kb ^ ((r >> 1) & 3)) << 4);
        int c = wc * 64 + mi * 16 + (l & 15);
        boff[mi] = 8192 + c * 64 + ((kb ^ ((c >> 1) & 3)) << 4);
    }

    f32x4 acc[4][4] = {};
    for (int k0 = 0; k0 < K; k0 += 32) {
        gload_lds16(pa1 + k0, la1);
        gload_lds16(pa2 + k0, la2);
        gload_lds16(pb1 + k0, lb1);
        gload_lds16(pb2 + k0, lb2);
        __syncthreads();
        short8v a[4], b[4];
        #pragma unroll
        for (int mi = 0; mi < 4; ++mi) a[mi] = *(const short8v*)(lds + aoff[mi]);
        #pragma unroll
        for (int ni = 0; ni < 4; ++ni) b[ni] = *(const short8v*)(lds + boff[ni]);
        #pragma unroll
        for (int mi = 0; mi < 4; ++mi)
            #pragma unroll
            for (int ni = 0; ni < 4; ++ni)
                acc[mi][ni] = __builtin_amdgcn_mfma_f32_16x16x32_bf16(
                    a[mi], b[ni], acc[mi][ni], 0, 0, 0);
        __syncthreads();
    }

    ushort_t* C = (bn < 256) ? C0 : C1;
    const float* bias = (bn < 256) ? bias0 : bias1;
    const int cb = (bn < 256) ? bn : bn - 256;
    #pragma unroll
    for (int mi = 0; mi < 4; ++mi) {
        int row = bm + wr * 64 + mi * 16 + (l >> 4) * 4;
        #pragma unroll
        for (int ni = 0; ni < 4; ++ni) {
            int col = cb + wc * 64 + ni * 16 + (l & 15);
            float bv = bias ? bias[col] : 0.f;
            #pragma unroll
            for (int r = 0; r < 4; ++r) {
                if (row + r < M)
                    C[(size_t)(row + r) * HID + col] = f2bf(acc[mi][ni][r] + bv);
            }
        }
    }
}

// ---------------------------------------------------------------- attention scores
__global__ __launch_bounds__(256) void k_scores(const ushort_t* __restrict__ xhb,
                                                const float* __restrict__ a_src,
                                                const float* __restrict__ a_dst,
                                                float* __restrict__ asn,
                                                float* __restrict__ adn) {
    int wave = threadIdx.x >> 6, lane = threadIdx.x & 63;
    int n = blockIdx.x * 4 + wave;
    if (n >= N_NODES) return;
    int head = lane >> 3, part = lane & 7;
    ushort4 u = *(const ushort4*)(xhb + (size_t)n * HID + head * CDIM + part * 4);
    float vx = bf2f(u.x), vy = bf2f(u.y), vz = bf2f(u.z), vw = bf2f(u.w);
    const float4 ws = *(const float4*)(a_src + head * CDIM + part * 4);
    const float4 wd = *(const float4*)(a_dst + head * CDIM + part * 4);
    float ds_ = vx * ws.x + vy * ws.y + vz * ws.z + vw * ws.w;
    float dd_ = vx * wd.x + vy * wd.y + vz * wd.z + vw * wd.w;
    for (int d = 1; d < 8; d <<= 1) {
        ds_ += __shfl_xor(ds_, d);
        dd_ += __shfl_xor(dd_, d);
    }
    if (part == 0) {
        asn[n * HEADS + head] = ds_;
        adn[n * HEADS + head] = dd_;
    }
}

// ---------------------------------------------------------------- aggregation + residual + LN + ReLU
// No max-subtraction (scores bounded ~|8|, exp safe in fp32; alphas identical).
// Edge loop unrolled x4 with all gathers issued before use (latency hiding).
__global__ __launch_bounds__(256) void k_agg_ln(const ushort_t* __restrict__ xhb,
                                                const float* __restrict__ asn,
                                                const float* __restrict__ adn,
                                                const int* __restrict__ rowptr,
                                                const int* __restrict__ colv,
                                                const ushort_t* __restrict__ hresb,
                                                const float* __restrict__ gb,
                                                const float* __restrict__ g,
                                                const float* __restrict__ b,
                                                ushort_t* __restrict__ hb) {
    int wave = threadIdx.x >> 6, lane = threadIdx.x & 63;
    int n = blockIdx.x * 4 + wave;
    if (n >= N_NODES) return;
    int head = lane >> 3, part = lane & 7;
    int c0 = head * CDIM + part * 4;
    float adn_h = adn[n * HEADS + head];
    int j0 = rowptr[n], j1 = rowptr[n + 1];
    float den = 0.f;
    float a0 = 0.f, a1 = 0.f, a2 = 0.f, a3 = 0.f;
    int j = j0;
    for (; j + 3 < j1; j += 4) {
        int s0 = colv[j], s1 = colv[j + 1], s2 = colv[j + 2], s3 = colv[j + 3];
        ushort4 u0 = *(const ushort4*)(xhb + (size_t)s0 * HID + c0);
        ushort4 u1 = *(const ushort4*)(xhb + (size_t)s1 * HID + c0);
        ushort4 u2 = *(const ushort4*)(xhb + (size_t)s2 * HID + c0);
        ushort4 u3 = *(const ushort4*)(xhb + (size_t)s3 * HID + c0);
        float e0 = asn[s0 * HEADS + head] + adn_h;
        float e1 = asn[s1 * HEADS + head] + adn_h;
        float e2 = asn[s2 * HEADS + head] + adn_h;
        float e3 = asn[s3 * HEADS + head] + adn_h;
        e0 = (e0 > 0.f) ? e0 : 0.2f * e0;
        e1 = (e1 > 0.f) ? e1 : 0.2f * e1;
        e2 = (e2 > 0.f) ? e2 : 0.2f * e2;
        e3 = (e3 > 0.f) ? e3 : 0.2f * e3;
        float p0 = __expf(e0), p1 = __expf(e1), p2 = __expf(e2), p3 = __expf(e3);
        den += (p0 + p1) + (p2 + p3);
        a0 += p0 * bf2f(u0.x) + p1 * bf2f(u1.x) + p2 * bf2f(u2.x) + p3 * bf2f(u3.x);
        a1 += p0 * bf2f(u0.y) + p1 * bf2f(u1.y) + p2 * bf2f(u2.y) + p3 * bf2f(u3.y);
        a2 += p0 * bf2f(u0.z) + p1 * bf2f(u1.z) + p2 * bf2f(u2.z) + p3 * bf2f(u3.z);
        a3 += p0 * bf2f(u0.w) + p1 * bf2f(u1.w) + p2 * bf2f(u2.w) + p3 * bf2f(u3.w);
    }
    for (; j < j1; ++j) {
        int s = colv[j];
        ushort4 u = *(const ushort4*)(xhb + (size_t)s * HID + c0);
        float e = asn[s * HEADS + head] + adn_h;
        e = (e > 0.f) ? e : 0.2f * e;
        float p = __expf(e);
        den += p;
        a0 += p * bf2f(u.x);
        a1 += p * bf2f(u.y);
        a2 += p * bf2f(u.z);
        a3 += p * bf2f(u.w);
    }
    float inv = 1.f / (den + 1e-16f);
    ushort4 hr = *(const ushort4*)(hresb + (size_t)n * HID + c0);
    float4 gb4 = *(const float4*)(gb + c0);
    float v0 = a0 * inv + bf2f(hr.x) + gb4.x;
    float v1 = a1 * inv + bf2f(hr.y) + gb4.y;
    float v2 = a2 * inv + bf2f(hr.z) + gb4.z;
    float v3 = a3 * inv + bf2f(hr.w) + gb4.w;
    float s = v0 + v1 + v2 + v3;
    for (int d = 1; d < 64; d <<= 1) s += __shfl_xor(s, d);
    float mu = s * (1.f / HID);
    float d0 = v0 - mu, d1 = v1 - mu, d2 = v2 - mu, d3 = v3 - mu;
    float q = d0 * d0 + d1 * d1 + d2 * d2 + d3 * d3;
    for (int d = 1; d < 64; d <<= 1) q += __shfl_xor(q, d);
    float rstd = rsqrtf(q * (1.f / HID) + LN_EPS);
    float4 gg = *(const float4*)(g + c0);
    float4 bb = *(const float4*)(b + c0);
    ushort_t o[4];
    o[0] = f2bf(fmaxf(d0 * rstd * gg.x + bb.x, 0.f));
    o[1] = f2bf(fmaxf(d1 * rstd * gg.y + bb.y, 0.f));
    o[2] = f2bf(fmaxf(d2 * rstd * gg.z + bb.z, 0.f));
    o[3] = f2bf(fmaxf(d3 * rstd * gg.w + bb.w, 0.f));
    *(ushort4*)(hb + (size_t)n * HID + c0) = *(ushort4*)o;
}

// ---------------------------------------------------------------- pooling (2-stage)
__global__ __launch_bounds__(256) void k_pool1(const ushort_t* __restrict__ hb,
                                               const int* __restrict__ rowstart,
                                               float* __restrict__ part) {
    int g = blockIdx.x, p = blockIdx.y, c = threadIdx.x;
    int s0 = rowstart[g], s1 = rowstart[g + 1];
    float sum = 0.f, mx = -INFINITY;
    for (int n = s0 + p; n < s1; n += POOL_P) {
        float v = bf2f(hb[(size_t)n * HID + c]);
        sum += v;
        mx = fmaxf(mx, v);
    }
    float* pp = part + (size_t)(g * POOL_P + p) * 512;
    pp[c] = sum;
    pp[256 + c] = mx;
}

__global__ __launch_bounds__(256) void k_pool2(const float* __restrict__ part,
                                               const int* __restrict__ rowstart,
                                               float* __restrict__ hcat) {
    int g = blockIdx.x, c = threadIdx.x;
    float sum = 0.f, mx = -INFINITY;
    for (int p = 0; p < POOL_P; ++p) {
        const float* pp = part + (size_t)(g * POOL_P + p) * 512;
        sum += pp[c];
        mx = fmaxf(mx, pp[256 + c]);
    }
    float cntf = (float)(rowstart[g + 1] - rowstart[g]);
    hcat[(size_t)g * (2 * HID) + c] = sum / fmaxf(cntf, 1.f);
    hcat[(size_t)g * (2 * HID) + HID + c] = mx;
}

__global__ __launch_bounds__(256) void k_pool_gemm(const float* __restrict__ hcat,
                                                   const float* __restrict__ W,
                                                   const float* __restrict__ bias,
                                                   float* __restrict__ out) {
    int g = blockIdx.x, c = threadIdx.x;
    const float* hg = hcat + (size_t)g * (2 * HID);
    float acc = bias[c];
    for (int k = 0; k < 2 * HID; ++k)
        acc += hg[k] * W[(size_t)k * HID + c];
    out[(size_t)g * HID + c] = fmaxf(acc, 0.f);
}

// ---------------------------------------------------------------- launch
extern "C" void kernel_launch(void* const* d_in, const int* in_sizes, int n_in,
                              void* d_out, int out_size, void* d_ws, size_t ws_size,
                              hipStream_t stream) {
    const float* x       = (const float*)d_in[0];
    const int*   ei      = (const int*)d_in[1];
    const int*   batch   = (const int*)d_in[2];
    const float* in_w    = (const float*)d_in[3];
    const float* in_b    = (const float*)d_in[4];
    const float* gat_w   = (const float*)d_in[5];
    const float* att_src = (const float*)d_in[6];
    const float* att_dst = (const float*)d_in[7];
    const float* gat_b   = (const float*)d_in[8];
    const float* res_w   = (const float*)d_in[9];
    const float* res_b   = (const float*)d_in[10];
    const float* ln_g    = (const float*)d_in[11];
    const float* ln_b    = (const float*)d_in[12];
    const float* pool_w  = (const float*)d_in[13];
    const float* pool_b  = (const float*)d_in[14];
    float* out = (float*)d_out;

    char* ws = (char*)d_ws;
    size_t off = 0;
    auto alloc = [&](size_t bytes) -> char* {
        char* p = ws + off;
        off = (off + bytes + 255) & ~(size_t)255;
        return p;
    };
    ushort_t* xb    = (ushort_t*)alloc((size_t)M_PAD * FDIM * 2);
    ushort_t* hb    = (ushort_t*)alloc((size_t)M_PAD * HID * 2);
    ushort_t* xhb   = (ushort_t*)alloc((size_t)M_PAD * HID * 2);
    ushort_t* hresb = (ushort_t*)alloc((size_t)M_PAD * HID * 2);
    float* asn      = (float*)alloc((size_t)N_NODES * HEADS * 4);
    float* adn      = (float*)alloc((size_t)N_NODES * HEADS * 4);
    int*   cnt      = (int*)alloc((size_t)N_NODES * 4);
    int*   fill     = (int*)alloc((size_t)N_NODES * 4);
    int*   rowptr   = (int*)alloc((size_t)(N_NODES + 1) * 4);
    int*   colv     = (int*)alloc((size_t)E2 * 4);
    int*   part     = (int*)alloc(256 * 4);
    int*   rowstart = (int*)alloc((size_t)(GRAPHS + 1) * 4);
    ushort_t* wt_in = (ushort_t*)alloc((size_t)HID * FDIM * 2);
    ushort_t* wt2   = (ushort_t*)alloc((size_t)LAYERS * 512 * HID * 2); // [res;gat] transposed
    float* poolpart = (float*)alloc((size_t)GRAPHS * POOL_P * 512 * 4);
    float* hcat     = (float*)alloc((size_t)GRAPHS * 2 * HID * 4);

    hipMemsetAsync(cnt, 0, (size_t)N_NODES * 4, stream);
    hipMemsetAsync(fill, 0, (size_t)N_NODES * 4, stream);

    const int ge = (E2 + 255) / 256;
    const int nb = (N_NODES + 255) / 256;
    k_count<<<ge, 256, 0, stream>>>(ei, cnt);
    k_scan1<<<nb, 256, 0, stream>>>(cnt, part);
    k_scan2<<<1, 256, 0, stream>>>(part, nb, rowptr);
    k_scan3<<<nb, 256, 0, stream>>>(cnt, part, rowptr);
    k_fill<<<ge, 256, 0, stream>>>(ei, rowptr, fill, colv);
    k_bounds<<<nb, 256, 0, stream>>>(batch, rowstart);

    // conversions
    k_cast_x<<<(int)(((size_t)M_PAD * FDIM / 8 + 255) / 256), 256, 0, stream>>>(x, xb);
    k_wtrans<<<(FDIM * HID + 255) / 256, 256, 0, stream>>>(in_w, wt_in, FDIM);
    for (int i = 0; i < LAYERS; ++i) {
        ushort_t* w2 = wt2 + (size_t)i * 512 * HID;
        k_wtrans<<<(HID * HID + 255) / 256, 256, 0, stream>>>(
            res_w + (size_t)i * HID * HID, w2, HID);
        k_wtrans<<<(HID * HID + 255) / 256, 256, 0, stream>>>(
            gat_w + (size_t)i * HID * HID, w2 + (size_t)256 * HID, HID);
    }

    dim3 gg1(M_PAD / 128, 2);
    k_gemm_bf16<FDIM><<<gg1, 256, 0, stream>>>(xb, wt_in, in_b, nullptr,
                                               hb, nullptr, N_NODES);

    const int nw = (N_NODES + 3) / 4;
    dim3 gg2(M_PAD / 128, 4);
    for (int i = 0; i < LAYERS; ++i) {
        // fused: cols 0..255 = h @ res_w + res_b -> hresb ; cols 256..511 = h @ gat_w -> xhb
        k_gemm_bf16<HID><<<gg2, 256, 0, stream>>>(hb, wt2 + (size_t)i * 512 * HID,
                                                  res_b + (size_t)i * HID, nullptr,
                                                  hresb, xhb, N_NODES);
        k_scores<<<nw, 256, 0, stream>>>(xhb, att_src + (size_t)i * HEADS * CDIM,
                                         att_dst + (size_t)i * HEADS * CDIM, asn, adn);
        k_agg_ln<<<nw, 256, 0, stream>>>(xhb, asn, adn, rowptr, colv, hresb,
                                         gat_b + (size_t)i * HID,
                                         ln_g + (size_t)i * HID,
                                         ln_b + (size_t)i * HID, hb);
    }
    dim3 pg(GRAPHS, POOL_P);
    k_pool1<<<pg, 256, 0, stream>>>(hb, rowstart, poolpart);
    k_pool2<<<GRAPHS, 256, 0, stream>>>(poolpart, rowstart, hcat);
    k_pool_gemm<<<GRAPHS, 256, 0, stream>>>(hcat, pool_w, pool_b, out);
}

// Round 4
// 587.481 us; speedup vs baseline: 2.6575x; 1.0378x over previous
//
#include <hip/hip_runtime.h>
#include <math.h>

#define N_NODES 50000
#define E_EDGES 800000
#define E2 (E_EDGES + N_NODES)   // 850000 with self loops
#define M_PAD 50048              // 391 * 128
#define FDIM 512
#define HID 256
#define HEADS 8
#define CDIM 32
#define LAYERS 3
#define GRAPHS 64
#define LN_EPS 1e-5f
#define POOL_P 16

typedef unsigned short ushort_t;
typedef __attribute__((ext_vector_type(8))) short short8v;
typedef __attribute__((ext_vector_type(4))) float f32x4;

__device__ __forceinline__ float bf2f(ushort_t u) {
    union { unsigned int i; float f; } v;
    v.i = ((unsigned int)u) << 16;
    return v.f;
}
__device__ __forceinline__ ushort_t f2bf(float f) {
    union { float f; unsigned int u; } v;
    v.f = f;
    unsigned int r = (v.u + 0x7FFFu + ((v.u >> 16) & 1u)) >> 16;
    return (ushort_t)r;
}
__device__ __forceinline__ void gload_lds16(const void* g, void* l) {
    __builtin_amdgcn_global_load_lds(
        (const __attribute__((address_space(1))) void*)g,
        (__attribute__((address_space(3))) void*)l, 16, 0, 0);
}

// ---------------------------------------------------------------- CSR build
__global__ void k_count(const int* __restrict__ ei, int* __restrict__ cnt) {
    int e = blockIdx.x * 256 + threadIdx.x;
    if (e >= E2) return;
    int dst = (e < E_EDGES) ? ei[E_EDGES + e] : (e - E_EDGES);
    atomicAdd(&cnt[dst], 1);
}

__global__ void k_scan1(const int* __restrict__ cnt, int* __restrict__ part) {
    __shared__ int s[256];
    int t = threadIdx.x;
    int i = blockIdx.x * 256 + t;
    s[t] = (i < N_NODES) ? cnt[i] : 0;
    __syncthreads();
    for (int d = 128; d > 0; d >>= 1) {
        if (t < d) s[t] += s[t + d];
        __syncthreads();
    }
    if (t == 0) part[blockIdx.x] = s[0];
}

__global__ void k_scan2(int* __restrict__ part, int nb, int* __restrict__ rowptr) {
    __shared__ int s[256];
    int t = threadIdx.x;
    int v = (t < nb) ? part[t] : 0;
    s[t] = v;
    __syncthreads();
    for (int d = 1; d < 256; d <<= 1) {
        int x = (t >= d) ? s[t - d] : 0;
        __syncthreads();
        s[t] += x;
        __syncthreads();
    }
    if (t < nb) part[t] = s[t] - v;
    if (t == 255) rowptr[N_NODES] = s[255];
}

__global__ void k_scan3(const int* __restrict__ cnt, const int* __restrict__ part,
                        int* __restrict__ rowptr) {
    __shared__ int s[256];
    int t = threadIdx.x;
    int i = blockIdx.x * 256 + t;
    int v = (i < N_NODES) ? cnt[i] : 0;
    s[t] = v;
    __syncthreads();
    for (int d = 1; d < 256; d <<= 1) {
        int x = (t >= d) ? s[t - d] : 0;
        __syncthreads();
        s[t] += x;
        __syncthreads();
    }
    if (i < N_NODES) rowptr[i] = part[blockIdx.x] + s[t] - v;
}

__global__ void k_fill(const int* __restrict__ ei, const int* __restrict__ rowptr,
                       int* __restrict__ fill, int* __restrict__ colv) {
    int e = blockIdx.x * 256 + threadIdx.x;
    if (e >= E2) return;
    int src, dst;
    if (e < E_EDGES) { src = ei[e]; dst = ei[E_EDGES + e]; }
    else             { src = dst = e - E_EDGES; }
    int pos = atomicAdd(&fill[dst], 1);
    colv[rowptr[dst] + pos] = src;
}

__global__ void k_bounds(const int* __restrict__ batch, int* __restrict__ rowstart) {
    int n = blockIdx.x * 256 + threadIdx.x;
    if (n >= N_NODES) return;
    int b = batch[n];
    int bp = (n == 0) ? -1 : batch[n - 1];
    for (int g = bp + 1; g <= b; ++g) rowstart[g] = n;
    if (n == N_NODES - 1) {
        for (int g = b + 1; g <= GRAPHS; ++g) rowstart[g] = N_NODES;
    }
}

// ---------------------------------------------------------------- conversions
__global__ __launch_bounds__(256) void k_cast_x(const float* __restrict__ x,
                                                ushort_t* __restrict__ xb) {
    long long i8 = ((long long)blockIdx.x * 256 + threadIdx.x) * 8;
    if (i8 >= (long long)M_PAD * FDIM) return;
    int row = (int)(i8 >> 9);
    ushort_t o[8];
    if (row < N_NODES) {
        const float* p = x + i8;
        #pragma unroll
        for (int j = 0; j < 8; ++j) o[j] = f2bf(p[j]);
    } else {
        #pragma unroll
        for (int j = 0; j < 8; ++j) o[j] = 0;
    }
    *(short8v*)(xb + i8) = *(short8v*)o;
}

// All weight transposes in one launch:
//  seg 0: in_w fp32 [512,256] -> wt_in bf16 [256,512]
//  seg 1: per layer, res_w -> wt2 rows 0..255, gat_w -> wt2 rows 256..511 ([n][K=256])
#define IN_ELEMS (FDIM * HID)
#define MAT_ELEMS (HID * HID)
#define WT_TOTAL (IN_ELEMS + 2 * LAYERS * MAT_ELEMS)
__global__ __launch_bounds__(256) void k_wtrans_all(const float* __restrict__ in_w,
                                                    const float* __restrict__ gat_w,
                                                    const float* __restrict__ res_w,
                                                    ushort_t* __restrict__ wt_in,
                                                    ushort_t* __restrict__ wt2) {
    int id = blockIdx.x * 256 + threadIdx.x;
    if (id >= WT_TOTAL) return;
    if (id < IN_ELEMS) {
        int k = id >> 8, n = id & 255;
        wt_in[(size_t)n * FDIM + k] = f2bf(in_w[id]);
    } else {
        int r = id - IN_ELEMS;
        int mat = r >> 16;            // 0..5
        int layer = mat >> 1;
        int isgat = mat & 1;
        int within = r & 65535;
        int k = within >> 8, n = within & 255;
        const float* W = (isgat ? gat_w : res_w) + (size_t)layer * MAT_ELEMS;
        wt2[(size_t)layer * 512 * HID + (size_t)(isgat * 256 + n) * HID + k] =
            f2bf(W[within]);
    }
}

// ---------------------------------------------------------------- bf16 MFMA GEMM
// C[:, bn..bn+127] of A[M_PAD,K] @ BT^T, BT bf16 [NCOLS,K] (row n = output col n).
// Logical col < 256 -> C0 (+bias0), >= 256 -> C1 at col-256 (+bias1). 128x128 tile.
template<int K>
__global__ __launch_bounds__(256) void k_gemm_bf16(const ushort_t* __restrict__ A,
                                                   const ushort_t* __restrict__ BT,
                                                   const float* __restrict__ bias0,
                                                   const float* __restrict__ bias1,
                                                   ushort_t* __restrict__ C0,
                                                   ushort_t* __restrict__ C1, int M) {
    __shared__ char lds[16384] __attribute__((aligned(16)));
    const int bm = blockIdx.x * 128;
    const int bn = blockIdx.y * 128;
    const int t = threadIdx.x, w = t >> 6, l = t & 63;
    const int wr = w >> 1, wc = w & 1;

    const int c1 = t, c2 = t + 256;
    const int ar1 = c1 >> 2, as1 = (c1 & 3) ^ ((ar1 >> 1) & 3);
    const int ar2 = c2 >> 2, as2 = (c2 & 3) ^ ((ar2 >> 1) & 3);
    const ushort_t* pa1 = A + (size_t)(bm + ar1) * K + as1 * 8;
    const ushort_t* pa2 = A + (size_t)(bm + ar2) * K + as2 * 8;
    const ushort_t* pb1 = BT + (size_t)(bn + ar1) * K + as1 * 8;
    const ushort_t* pb2 = BT + (size_t)(bn + ar2) * K + as2 * 8;
    char* la1 = lds + w * 1024;
    char* la2 = lds + 4096 + w * 1024;
    char* lb1 = lds + 8192 + w * 1024;
    char* lb2 = lds + 12288 + w * 1024;

    int aoff[4], boff[4];
    const int kb = l >> 4;
    #pragma unroll
    for (int mi = 0; mi < 4; ++mi) {
        int r = wr * 64 + mi * 16 + (l & 15);
        aoff[mi] = r * 64 + ((kb ^ ((r >> 1) & 3)) << 4);
        int c = wc * 64 + mi * 16 + (l & 15);
        boff[mi] = 8192 + c * 64 + ((kb ^ ((c >> 1) & 3)) << 4);
    }

    f32x4 acc[4][4] = {};
    for (int k0 = 0; k0 < K; k0 += 32) {
        gload_lds16(pa1 + k0, la1);
        gload_lds16(pa2 + k0, la2);
        gload_lds16(pb1 + k0, lb1);
        gload_lds16(pb2 + k0, lb2);
        __syncthreads();
        short8v a[4], b[4];
        #pragma unroll
        for (int mi = 0; mi < 4; ++mi) a[mi] = *(const short8v*)(lds + aoff[mi]);
        #pragma unroll
        for (int ni = 0; ni < 4; ++ni) b[ni] = *(const short8v*)(lds + boff[ni]);
        #pragma unroll
        for (int mi = 0; mi < 4; ++mi)
            #pragma unroll
            for (int ni = 0; ni < 4; ++ni)
                acc[mi][ni] = __builtin_amdgcn_mfma_f32_16x16x32_bf16(
                    a[mi], b[ni], acc[mi][ni], 0, 0, 0);
        __syncthreads();
    }

    ushort_t* C = (bn < 256) ? C0 : C1;
    const float* bias = (bn < 256) ? bias0 : bias1;
    const int cb = (bn < 256) ? bn : bn - 256;
    #pragma unroll
    for (int mi = 0; mi < 4; ++mi) {
        int row = bm + wr * 64 + mi * 16 + (l >> 4) * 4;
        #pragma unroll
        for (int ni = 0; ni < 4; ++ni) {
            int col = cb + wc * 64 + ni * 16 + (l & 15);
            float bv = bias ? bias[col] : 0.f;
            #pragma unroll
            for (int r = 0; r < 4; ++r) {
                if (row + r < M)
                    C[(size_t)(row + r) * HID + col] = f2bf(acc[mi][ni][r] + bv);
            }
        }
    }
}

// ---------------------------------------------------------------- attention scores
__global__ __launch_bounds__(256) void k_scores(const ushort_t* __restrict__ xhb,
                                                const float* __restrict__ a_src,
                                                const float* __restrict__ a_dst,
                                                float* __restrict__ asn,
                                                float* __restrict__ adn) {
    int wave = threadIdx.x >> 6, lane = threadIdx.x & 63;
    int n = blockIdx.x * 4 + wave;
    if (n >= N_NODES) return;
    int head = lane >> 3, part = lane & 7;
    ushort4 u = *(const ushort4*)(xhb + (size_t)n * HID + head * CDIM + part * 4);
    float vx = bf2f(u.x), vy = bf2f(u.y), vz = bf2f(u.z), vw = bf2f(u.w);
    const float4 ws = *(const float4*)(a_src + head * CDIM + part * 4);
    const float4 wd = *(const float4*)(a_dst + head * CDIM + part * 4);
    float ds_ = vx * ws.x + vy * ws.y + vz * ws.z + vw * ws.w;
    float dd_ = vx * wd.x + vy * wd.y + vz * wd.z + vw * wd.w;
    for (int d = 1; d < 8; d <<= 1) {
        ds_ += __shfl_xor(ds_, d);
        dd_ += __shfl_xor(dd_, d);
    }
    if (part == 0) {
        asn[n * HEADS + head] = ds_;
        adn[n * HEADS + head] = dd_;
    }
}

// ---------------------------------------------------------------- aggregation + residual + LN + ReLU
// 1 wave / node; lanes 0-31 = even edges, 32-63 = odd edges; each lane owns 8
// channels (16B gathers). Unroll x4 pairs -> 8 edges in flight. No max-sub
// (scores bounded, exp safe in fp32).
__global__ __launch_bounds__(256) void k_agg_ln(const ushort_t* __restrict__ xhb,
                                                const float* __restrict__ asn,
                                                const float* __restrict__ adn,
                                                const int* __restrict__ rowptr,
                                                const int* __restrict__ colv,
                                                const ushort_t* __restrict__ hresb,
                                                const float* __restrict__ gb,
                                                const float* __restrict__ g,
                                                const float* __restrict__ b,
                                                ushort_t* __restrict__ hb) {
    const int wave = threadIdx.x >> 6, lane = threadIdx.x & 63;
    const int n = blockIdx.x * 4 + wave;
    if (n >= N_NODES) return;
    const int half = lane >> 5;          // which edge of the pair
    const int lh = lane & 31;            // lane within half
    const int head = lh >> 2;            // 4 lanes per head per half
    const int ch0 = lh * 8;              // 8 channels per lane
    const float adn_h = adn[n * HEADS + head];
    const int j0 = rowptr[n], j1 = rowptr[n + 1];

    float acc[8] = {};
    float den = 0.f;
    int base = j0;
    for (; base + 8 <= j1; base += 8) {
        int idx[4];
        #pragma unroll
        for (int q = 0; q < 4; ++q) idx[q] = colv[base + 2 * q + half];
        short8v u[4];
        #pragma unroll
        for (int q = 0; q < 4; ++q)
            u[q] = *(const short8v*)(xhb + (size_t)idx[q] * HID + ch0);
        float p[4];
        #pragma unroll
        for (int q = 0; q < 4; ++q) {
            float e = asn[idx[q] * HEADS + head] + adn_h;
            e = (e > 0.f) ? e : 0.2f * e;
            p[q] = __expf(e);
        }
        #pragma unroll
        for (int q = 0; q < 4; ++q) {
            den += p[q];
            #pragma unroll
            for (int c = 0; c < 8; ++c)
                acc[c] += p[q] * bf2f((ushort_t)u[q][c]);
        }
    }
    for (; base < j1; base += 2) {
        bool valid = (base + half) < j1;
        int s = valid ? colv[base + half] : n;
        short8v u = *(const short8v*)(xhb + (size_t)s * HID + ch0);
        float e = asn[s * HEADS + head] + adn_h;
        e = (e > 0.f) ? e : 0.2f * e;
        float p = valid ? __expf(e) : 0.f;
        den += p;
        #pragma unroll
        for (int c = 0; c < 8; ++c)
            acc[c] += p * bf2f((ushort_t)u[c]);
    }
    // merge halves (lane l and l+32 hold same channels)
    den += __shfl_xor(den, 32);
    #pragma unroll
    for (int c = 0; c < 8; ++c) acc[c] += __shfl_xor(acc[c], 32);

    const float inv = 1.f / (den + 1e-16f);
    short8v hr = *(const short8v*)(hresb + (size_t)n * HID + ch0);
    float4 gbA = *(const float4*)(gb + ch0);
    float4 gbB = *(const float4*)(gb + ch0 + 4);
    float v[8];
    #pragma unroll
    for (int c = 0; c < 8; ++c) {
        float gbv = (c < 4) ? ((const float*)&gbA)[c] : ((const float*)&gbB)[c - 4];
        v[c] = acc[c] * inv + bf2f((ushort_t)hr[c]) + gbv;
    }
    float s = 0.f;
    #pragma unroll
    for (int c = 0; c < 8; ++c) s += v[c];
    #pragma unroll
    for (int d = 1; d < 32; d <<= 1) s += __shfl_xor(s, d);   // within each half
    const float mu = s * (1.f / HID);
    float q = 0.f;
    #pragma unroll
    for (int c = 0; c < 8; ++c) {
        v[c] -= mu;
        q += v[c] * v[c];
    }
    #pragma unroll
    for (int d = 1; d < 32; d <<= 1) q += __shfl_xor(q, d);
    const float rstd = rsqrtf(q * (1.f / HID) + LN_EPS);
    float4 gA = *(const float4*)(g + ch0);
    float4 gB = *(const float4*)(g + ch0 + 4);
    float4 bA = *(const float4*)(b + ch0);
    float4 bB = *(const float4*)(b + ch0 + 4);
    ushort_t o[8];
    #pragma unroll
    for (int c = 0; c < 8; ++c) {
        float gv = (c < 4) ? ((const float*)&gA)[c] : ((const float*)&gB)[c - 4];
        float bv = (c < 4) ? ((const float*)&bA)[c] : ((const float*)&bB)[c - 4];
        o[c] = f2bf(fmaxf(v[c] * rstd * gv + bv, 0.f));
    }
    if (half == 0)
        *(short8v*)(hb + (size_t)n * HID + ch0) = *(short8v*)o;
}

// ---------------------------------------------------------------- pooling (2-stage)
__global__ __launch_bounds__(256) void k_pool1(const ushort_t* __restrict__ hb,
                                               const int* __restrict__ rowstart,
                                               float* __restrict__ part) {
    int g = blockIdx.x, p = blockIdx.y, c = threadIdx.x;
    int s0 = rowstart[g], s1 = rowstart[g + 1];
    float sum = 0.f, mx = -INFINITY;
    for (int n = s0 + p; n < s1; n += POOL_P) {
        float v = bf2f(hb[(size_t)n * HID + c]);
        sum += v;
        mx = fmaxf(mx, v);
    }
    float* pp = part + (size_t)(g * POOL_P + p) * 512;
    pp[c] = sum;
    pp[256 + c] = mx;
}

__global__ __launch_bounds__(256) void k_pool2(const float* __restrict__ part,
                                               const int* __restrict__ rowstart,
                                               float* __restrict__ hcat) {
    int g = blockIdx.x, c = threadIdx.x;
    float sum = 0.f, mx = -INFINITY;
    for (int p = 0; p < POOL_P; ++p) {
        const float* pp = part + (size_t)(g * POOL_P + p) * 512;
        sum += pp[c];
        mx = fmaxf(mx, pp[256 + c]);
    }
    float cntf = (float)(rowstart[g + 1] - rowstart[g]);
    hcat[(size_t)g * (2 * HID) + c] = sum / fmaxf(cntf, 1.f);
    hcat[(size_t)g * (2 * HID) + HID + c] = mx;
}

__global__ __launch_bounds__(256) void k_pool_gemm(const float* __restrict__ hcat,
                                                   const float* __restrict__ W,
                                                   const float* __restrict__ bias,
                                                   float* __restrict__ out) {
    int g = blockIdx.x, c = threadIdx.x;
    const float* hg = hcat + (size_t)g * (2 * HID);
    float acc = bias[c];
    for (int k = 0; k < 2 * HID; ++k)
        acc += hg[k] * W[(size_t)k * HID + c];
    out[(size_t)g * HID + c] = fmaxf(acc, 0.f);
}

// ---------------------------------------------------------------- launch
extern "C" void kernel_launch(void* const* d_in, const int* in_sizes, int n_in,
                              void* d_out, int out_size, void* d_ws, size_t ws_size,
                              hipStream_t stream) {
    const float* x       = (const float*)d_in[0];
    const int*   ei      = (const int*)d_in[1];
    const int*   batch   = (const int*)d_in[2];
    const float* in_w    = (const float*)d_in[3];
    const float* in_b    = (const float*)d_in[4];
    const float* gat_w   = (const float*)d_in[5];
    const float* att_src = (const float*)d_in[6];
    const float* att_dst = (const float*)d_in[7];
    const float* gat_b   = (const float*)d_in[8];
    const float* res_w   = (const float*)d_in[9];
    const float* res_b   = (const float*)d_in[10];
    const float* ln_g    = (const float*)d_in[11];
    const float* ln_b    = (const float*)d_in[12];
    const float* pool_w  = (const float*)d_in[13];
    const float* pool_b  = (const float*)d_in[14];
    float* out = (float*)d_out;

    char* ws = (char*)d_ws;
    size_t off = 0;
    auto alloc = [&](size_t bytes) -> char* {
        char* p = ws + off;
        off = (off + bytes + 255) & ~(size_t)255;
        return p;
    };
    ushort_t* xb    = (ushort_t*)alloc((size_t)M_PAD * FDIM * 2);
    ushort_t* hb    = (ushort_t*)alloc((size_t)M_PAD * HID * 2);
    ushort_t* xhb   = (ushort_t*)alloc((size_t)M_PAD * HID * 2);
    ushort_t* hresb = (ushort_t*)alloc((size_t)M_PAD * HID * 2);
    float* asn      = (float*)alloc((size_t)N_NODES * HEADS * 4);
    float* adn      = (float*)alloc((size_t)N_NODES * HEADS * 4);
    int*   cnt      = (int*)alloc((size_t)N_NODES * 4);
    int*   fill     = (int*)alloc((size_t)N_NODES * 4);
    int*   rowptr   = (int*)alloc((size_t)(N_NODES + 1) * 4);
    int*   colv     = (int*)alloc((size_t)E2 * 4);
    int*   part     = (int*)alloc(256 * 4);
    int*   rowstart = (int*)alloc((size_t)(GRAPHS + 1) * 4);
    ushort_t* wt_in = (ushort_t*)alloc((size_t)HID * FDIM * 2);
    ushort_t* wt2   = (ushort_t*)alloc((size_t)LAYERS * 512 * HID * 2); // [res;gat] transposed
    float* poolpart = (float*)alloc((size_t)GRAPHS * POOL_P * 512 * 4);
    float* hcat     = (float*)alloc((size_t)GRAPHS * 2 * HID * 4);

    hipMemsetAsync(cnt, 0, (size_t)N_NODES * 4, stream);
    hipMemsetAsync(fill, 0, (size_t)N_NODES * 4, stream);

    const int ge = (E2 + 255) / 256;
    const int nb = (N_NODES + 255) / 256;
    k_count<<<ge, 256, 0, stream>>>(ei, cnt);
    k_scan1<<<nb, 256, 0, stream>>>(cnt, part);
    k_scan2<<<1, 256, 0, stream>>>(part, nb, rowptr);
    k_scan3<<<nb, 256, 0, stream>>>(cnt, part, rowptr);
    k_fill<<<ge, 256, 0, stream>>>(ei, rowptr, fill, colv);
    k_bounds<<<nb, 256, 0, stream>>>(batch, rowstart);

    // conversions
    k_cast_x<<<(int)(((size_t)M_PAD * FDIM / 8 + 255) / 256), 256, 0, stream>>>(x, xb);
    k_wtrans_all<<<(WT_TOTAL + 255) / 256, 256, 0, stream>>>(in_w, gat_w, res_w,
                                                             wt_in, wt2);

    dim3 gg1(M_PAD / 128, 2);
    k_gemm_bf16<FDIM><<<gg1, 256, 0, stream>>>(xb, wt_in, in_b, nullptr,
                                               hb, nullptr, N_NODES);

    const int nw = (N_NODES + 3) / 4;
    dim3 gg2(M_PAD / 128, 4);
    for (int i = 0; i < LAYERS; ++i) {
        // fused: cols 0..255 = h @ res_w + res_b -> hresb ; cols 256..511 = h @ gat_w -> xhb
        k_gemm_bf16<HID><<<gg2, 256, 0, stream>>>(hb, wt2 + (size_t)i * 512 * HID,
                                                  res_b + (size_t)i * HID, nullptr,
                                                  hresb, xhb, N_NODES);
        k_scores<<<nw, 256, 0, stream>>>(xhb, att_src + (size_t)i * HEADS * CDIM,
                                         att_dst + (size_t)i * HEADS * CDIM, asn, adn);
        k_agg_ln<<<nw, 256, 0, stream>>>(xhb, asn, adn, rowptr, colv, hresb,
                                         gat_b + (size_t)i * HID,
                                         ln_g + (size_t)i * HID,
                                         ln_b + (size_t)i * HID, hb);
    }
    dim3 pg(GRAPHS, POOL_P);
    k_pool1<<<pg, 256, 0, stream>>>(hb, rowstart, poolpart);
    k_pool2<<<GRAPHS, 256, 0, stream>>>(poolpart, rowstart, hcat);
    k_pool_gemm<<<GRAPHS, 256, 0, stream>>>(hcat, pool_w, pool_b, out);
}